// Round 1
// baseline (1715.097 us; speedup 1.0000x reference)
//
#include <hip/hip_runtime.h>
#include <hip/hip_bf16.h>

// Collapsed algebra:
//   out[i] = s * (A^12 x)[i] + t * (A^11 1)[i] + b11
// where A = D^{-1/2} (W + I) D^{-1/2} (self loops weight 1),
//   v = O_0 (O_1 (... (O_9 W11))),  O_k = Taylor_10(expm(Wk - Wk^T))
//   s = W0 . v,  t = b0 . v

#define TPB 256

// ---------------- v-chain: 100 sequential 64x64 matvecs, one block ----------
__device__ void v_chain(const float* __restrict__ W_orth,
                        const float* __restrict__ W11,
                        const float* __restrict__ W0,
                        const float* __restrict__ b0,
                        float* __restrict__ scal) {
    __shared__ float S[64 * 65];   // padded to kill bank conflicts
    __shared__ float uvec[64];
    __shared__ float term[64];
    __shared__ float accv[64];
    const int tid = threadIdx.x;   // 256 threads

    if (tid < 64) uvec[tid] = W11[tid];
    __syncthreads();

    for (int k = 9; k >= 0; --k) {
        const float* Wk = W_orth + k * 4096;
        // S = Wk - Wk^T (into padded LDS)
        for (int e = tid; e < 4096; e += 256) {
            int i = e >> 6, j = e & 63;
            S[i * 65 + j] = Wk[i * 64 + j] - Wk[j * 64 + i];
        }
        __syncthreads();
        if (tid < 64) { term[tid] = uvec[tid]; accv[tid] = uvec[tid]; }
        __syncthreads();
        for (int t = 1; t <= 10; ++t) {
            const int r = tid >> 2, q = tid & 3;
            const int jb = q * 16;
            float p = 0.f;
            #pragma unroll
            for (int jj = 0; jj < 16; ++jj)
                p += S[r * 65 + jb + jj] * term[jb + jj];
            p += __shfl_xor(p, 1);
            p += __shfl_xor(p, 2);
            __syncthreads();                 // all reads of term done
            if (q == 0) {
                float nt = p / (float)t;
                term[r] = nt;
                accv[r] += nt;
            }
            __syncthreads();
        }
        if (tid < 64) uvec[tid] = accv[tid];
        __syncthreads();
    }
    if (tid < 64) {
        float a = W0[tid] * uvec[tid];
        float b = b0[tid] * uvec[tid];
        #pragma unroll
        for (int off = 32; off; off >>= 1) {
            a += __shfl_down(a, off);
            b += __shfl_down(b, off);
        }
        if (tid == 0) { scal[0] = a; scal[1] = b; }
    }
}

// ---------------- kernels ---------------------------------------------------
__global__ void k_init(const float* __restrict__ x, float* __restrict__ deg,
                       float2* __restrict__ y, int N) {
    int i = blockIdx.x * blockDim.x + threadIdx.x;
    if (i < N) {
        deg[i] = 1.0f;                        // self-loop weight
        y[i] = make_float2(x[i], 1.0f);       // [x-channel, ones-channel]
    }
}

__global__ void k_deg_and_v(const int* __restrict__ ei, const float* __restrict__ w,
                            int E, float* __restrict__ deg,
                            const float* __restrict__ W_orth,
                            const float* __restrict__ W11,
                            const float* __restrict__ W0,
                            const float* __restrict__ b0,
                            float* __restrict__ scal, int edge_blocks) {
    if ((int)blockIdx.x == edge_blocks) {     // last block: Taylor v-chain
        v_chain(W_orth, W11, W0, b0, scal);
        return;
    }
    int e = blockIdx.x * blockDim.x + threadIdx.x;
    if (e < E) atomicAdd(&deg[ei[E + e]], w[e]);
}

__global__ void k_norm(const int* __restrict__ ei, const float* __restrict__ w,
                       int E, const float* __restrict__ deg,
                       float* __restrict__ nrm) {
    int e = blockIdx.x * blockDim.x + threadIdx.x;
    if (e < E) {
        int r = ei[e], c = ei[E + e];
        nrm[e] = w[e] * rsqrtf(deg[r] * deg[c]);
    }
}

// self-loop contribution initializes the accumulator
__global__ void k_self(const float2* __restrict__ y, const float* __restrict__ deg,
                       float2* __restrict__ out, int N) {
    int i = blockIdx.x * blockDim.x + threadIdx.x;
    if (i < N) {
        float inv = 1.0f / deg[i];
        float2 v = y[i];
        out[i] = make_float2(v.x * inv, v.y * inv);
    }
}

__global__ void k_scatter(const int* __restrict__ ei, const float* __restrict__ nrm,
                          const float2* __restrict__ y, float* __restrict__ out,
                          int E) {
    int e = blockIdx.x * blockDim.x + threadIdx.x;
    if (e < E) {
        int r = ei[e], c = ei[E + e];
        float n = nrm[e];
        float2 v = y[r];
        atomicAdd(out + 2 * c,     n * v.x);
        atomicAdd(out + 2 * c + 1, n * v.y);
    }
}

__global__ void k_final(const float2* __restrict__ y12, const float2* __restrict__ y11,
                        const float* __restrict__ scal, const float* __restrict__ b11,
                        float* __restrict__ out, int N) {
    int i = blockIdx.x * blockDim.x + threadIdx.x;
    if (i < N)
        out[i] = scal[0] * y12[i].x + scal[1] * y11[i].y + b11[0];
}

// ---------------- launch ----------------------------------------------------
extern "C" void kernel_launch(void* const* d_in, const int* in_sizes, int n_in,
                              void* d_out, int out_size, void* d_ws, size_t ws_size,
                              hipStream_t stream) {
    const float* x      = (const float*)d_in[0];
    const int*   ei     = (const int*)d_in[1];
    const float* w      = (const float*)d_in[2];
    const float* W0     = (const float*)d_in[3];
    const float* b0     = (const float*)d_in[4];
    const float* W_orth = (const float*)d_in[5];
    const float* W11    = (const float*)d_in[6];
    const float* b11    = (const float*)d_in[7];

    const int N = in_sizes[0];          // 200000 (x is [N,1])
    const int E = in_sizes[2];          // 1200000

    // workspace layout
    char* ws = (char*)d_ws;
    float*  deg  = (float*)ws;                          ws += (size_t)N * 4;
    float*  nrm  = (float*)ws;                          ws += (size_t)E * 4;
    float2* yA   = (float2*)ws;                         ws += (size_t)N * 8;
    float2* yB   = (float2*)ws;                         ws += (size_t)N * 8;
    float*  scal = (float*)ws;                          ws += 16;

    const int NB = (N + TPB - 1) / TPB;
    const int EB = (E + TPB - 1) / TPB;

    k_init<<<NB, TPB, 0, stream>>>(x, deg, yA, N);
    k_deg_and_v<<<EB + 1, TPB, 0, stream>>>(ei, w, E, deg, W_orth, W11, W0, b0,
                                            scal, EB);
    k_norm<<<EB, TPB, 0, stream>>>(ei, w, E, deg, nrm);

    float2* prev = yA;
    float2* cur  = yB;
    for (int it = 0; it < 12; ++it) {
        k_self<<<NB, TPB, 0, stream>>>(prev, deg, cur, N);
        k_scatter<<<EB, TPB, 0, stream>>>(ei, nrm, prev, (float*)cur, E);
        float2* tmp = prev; prev = cur; cur = tmp;
    }
    // after the swap: prev = y12 (x-channel), cur = y11 (ones-channel)
    k_final<<<NB, TPB, 0, stream>>>(prev, cur, scal, b11, (float*)d_out, N);
}

// Round 2
// 477.941 us; speedup vs baseline: 3.5885x; 3.5885x over previous
//
#include <hip/hip_runtime.h>
#include <hip/hip_bf16.h>

// Collapsed algebra:
//   out[i] = s * (A^12 x)[i] + t * (A^11 1)[i] + b11
// where A = D^{-1/2} (W + I) D^{-1/2} (self loops weight 1),
//   v = O_0 (O_1 (... (O_9 W11))),  O_k = Taylor_10(expm(Wk - Wk^T))
//   s = W0 . v,  t = b0 . v
//
// R1: replace 12x edge-scatter (fp32 atomics, ~124us each) with a one-time
// CSR build (count + scan + fill) and 12x atomic-free node-parallel gathers.

#define TPB 256

// ---------------- v-chain: 100 sequential 64x64 matvecs, one block ----------
__device__ void v_chain(const float* __restrict__ W_orth,
                        const float* __restrict__ W11,
                        const float* __restrict__ W0,
                        const float* __restrict__ b0,
                        float* __restrict__ scal) {
    __shared__ float S[64 * 65];
    __shared__ float uvec[64];
    __shared__ float term[64];
    __shared__ float accv[64];
    const int tid = threadIdx.x;   // 256 threads

    if (tid < 64) uvec[tid] = W11[tid];
    __syncthreads();

    for (int k = 9; k >= 0; --k) {
        const float* Wk = W_orth + k * 4096;
        for (int e = tid; e < 4096; e += 256) {
            int i = e >> 6, j = e & 63;
            S[i * 65 + j] = Wk[i * 64 + j] - Wk[j * 64 + i];
        }
        __syncthreads();
        if (tid < 64) { term[tid] = uvec[tid]; accv[tid] = uvec[tid]; }
        __syncthreads();
        for (int t = 1; t <= 10; ++t) {
            const int r = tid >> 2, q = tid & 3;
            const int jb = q * 16;
            float p = 0.f;
            #pragma unroll
            for (int jj = 0; jj < 16; ++jj)
                p += S[r * 65 + jb + jj] * term[jb + jj];
            p += __shfl_xor(p, 1);
            p += __shfl_xor(p, 2);
            __syncthreads();
            if (q == 0) {
                float nt = p / (float)t;
                term[r] = nt;
                accv[r] += nt;
            }
            __syncthreads();
        }
        if (tid < 64) uvec[tid] = accv[tid];
        __syncthreads();
    }
    if (tid < 64) {
        float a = W0[tid] * uvec[tid];
        float b = b0[tid] * uvec[tid];
        #pragma unroll
        for (int off = 32; off; off >>= 1) {
            a += __shfl_down(a, off);
            b += __shfl_down(b, off);
        }
        if (tid == 0) { scal[0] = a; scal[1] = b; }
    }
}

// ---------------- kernels ---------------------------------------------------
__global__ void k_init(const float* __restrict__ x, float* __restrict__ deg,
                       int* __restrict__ cnt, float2* __restrict__ y, int N) {
    int i = blockIdx.x * blockDim.x + threadIdx.x;
    if (i < N) {
        deg[i] = 1.0f;                        // self-loop weight
        cnt[i] = 0;
        y[i] = make_float2(x[i], 1.0f);       // [x-channel, ones-channel]
    }
}

// per-edge: count in-edges + accumulate weighted degree (one-time atomics);
// last block runs the Taylor v-chain.
__global__ void k_count_deg(const int* __restrict__ ei, const float* __restrict__ w,
                            int E, float* __restrict__ deg, int* __restrict__ cnt,
                            const float* __restrict__ W_orth,
                            const float* __restrict__ W11,
                            const float* __restrict__ W0,
                            const float* __restrict__ b0,
                            float* __restrict__ scal, int edge_blocks) {
    if ((int)blockIdx.x == edge_blocks) {
        v_chain(W_orth, W11, W0, b0, scal);
        return;
    }
    int e = blockIdx.x * blockDim.x + threadIdx.x;
    if (e < E) {
        int c = ei[E + e];
        atomicAdd(&cnt[c], 1);
        atomicAdd(&deg[c], w[e]);
    }
}

// block-level inclusive scan of cnt -> off (partial), block sums -> bsum
__global__ void k_scan1(const int* __restrict__ cnt, int* __restrict__ off,
                        int* __restrict__ bsum, int N) {
    __shared__ int s[TPB];
    int t = threadIdx.x;
    int i = blockIdx.x * TPB + t;
    int v = (i < N) ? cnt[i] : 0;
    s[t] = v;
    __syncthreads();
    for (int o = 1; o < TPB; o <<= 1) {
        int u = (t >= o) ? s[t - o] : 0;
        __syncthreads();
        s[t] += u;
        __syncthreads();
    }
    if (i < N) off[i] = s[t];               // inclusive, block-local
    if (t == TPB - 1) bsum[blockIdx.x] = s[t];
}

// single-block exclusive scan of block sums (nb <= 1024)
__global__ void k_scan2(int* __restrict__ bsum, int nb) {
    __shared__ int s[1024];
    int t = threadIdx.x;
    int v = (t < nb) ? bsum[t] : 0;
    s[t] = v;
    __syncthreads();
    for (int o = 1; o < 1024; o <<= 1) {
        int u = (t >= o) ? s[t - o] : 0;
        __syncthreads();
        s[t] += u;
        __syncthreads();
    }
    if (t < nb) bsum[t] = s[t] - v;         // exclusive
}

// finalize: off -> global exclusive offsets; pos copy; dis/dinv from deg
__global__ void k_scan3(int* __restrict__ off, int* __restrict__ pos,
                        const int* __restrict__ cnt, const int* __restrict__ bsum,
                        const float* __restrict__ deg, float* __restrict__ dis,
                        float* __restrict__ dinv, int N, int E) {
    int i = blockIdx.x * blockDim.x + threadIdx.x;
    if (i < N) {
        int ex = off[i] - cnt[i] + bsum[blockIdx.x];
        off[i] = ex;
        pos[i] = ex;
        float d = deg[i];
        dis[i]  = rsqrtf(d);
        dinv[i] = 1.0f / d;
    }
    if (i == 0) off[N] = E;
}

// per-edge: place (src, norm) into CSR slot of its target
__global__ void k_fill(const int* __restrict__ ei, const float* __restrict__ w,
                       int E, const float* __restrict__ dis,
                       int* __restrict__ pos, int* __restrict__ csr_src,
                       float* __restrict__ csr_nrm) {
    int e = blockIdx.x * blockDim.x + threadIdx.x;
    if (e < E) {
        int r = ei[e], c = ei[E + e];
        float n = w[e] * dis[r] * dis[c];
        int p = atomicAdd(&pos[c], 1);
        csr_src[p] = r;
        csr_nrm[p] = n;
    }
}

// one propagation: out[i] = dinv[i]*y[i] + sum_e nrm[e]*y[src[e]]
__global__ void k_gather(const int* __restrict__ off, const int* __restrict__ csr_src,
                         const float* __restrict__ csr_nrm,
                         const float* __restrict__ dinv,
                         const float2* __restrict__ y, float2* __restrict__ out,
                         int N) {
    int i = blockIdx.x * blockDim.x + threadIdx.x;
    if (i >= N) return;
    int s = off[i], eend = off[i + 1];
    float2 yi = y[i];
    float di = dinv[i];
    float ax = yi.x * di, ay = yi.y * di;
    for (int k = s; k < eend; ++k) {
        int r = csr_src[k];
        float n = csr_nrm[k];
        float2 v = y[r];
        ax = fmaf(n, v.x, ax);
        ay = fmaf(n, v.y, ay);
    }
    out[i] = make_float2(ax, ay);
}

__global__ void k_final(const float2* __restrict__ y12, const float2* __restrict__ y11,
                        const float* __restrict__ scal, const float* __restrict__ b11,
                        float* __restrict__ out, int N) {
    int i = blockIdx.x * blockDim.x + threadIdx.x;
    if (i < N)
        out[i] = scal[0] * y12[i].x + scal[1] * y11[i].y + b11[0];
}

// ---------------- launch ----------------------------------------------------
extern "C" void kernel_launch(void* const* d_in, const int* in_sizes, int n_in,
                              void* d_out, int out_size, void* d_ws, size_t ws_size,
                              hipStream_t stream) {
    const float* x      = (const float*)d_in[0];
    const int*   ei     = (const int*)d_in[1];
    const float* w      = (const float*)d_in[2];
    const float* W0     = (const float*)d_in[3];
    const float* b0     = (const float*)d_in[4];
    const float* W_orth = (const float*)d_in[5];
    const float* W11    = (const float*)d_in[6];
    const float* b11    = (const float*)d_in[7];

    const int N = in_sizes[0];          // 200000
    const int E = in_sizes[2];          // 1200000

    // workspace layout (8B-aligned chunks first)
    char* ws = (char*)d_ws;
    float2* yA      = (float2*)ws;  ws += (size_t)N * 8;
    float2* yB      = (float2*)ws;  ws += (size_t)N * 8;
    int*    csr_src = (int*)ws;     ws += (size_t)E * 4;
    float*  csr_nrm = (float*)ws;   ws += (size_t)E * 4;
    int*    cnt     = (int*)ws;     ws += (size_t)N * 4;
    float*  deg     = (float*)ws;   ws += (size_t)N * 4;
    int*    off     = (int*)ws;     ws += (size_t)(N + 2) * 4;
    int*    pos     = (int*)ws;     ws += (size_t)N * 4;
    float*  dis     = (float*)ws;   ws += (size_t)N * 4;
    float*  dinv    = (float*)ws;   ws += (size_t)N * 4;
    int*    bsum    = (int*)ws;     ws += 1024 * 4;
    float*  scal    = (float*)ws;   ws += 16;

    const int NB = (N + TPB - 1) / TPB;
    const int EB = (E + TPB - 1) / TPB;

    k_init<<<NB, TPB, 0, stream>>>(x, deg, cnt, yA, N);
    k_count_deg<<<EB + 1, TPB, 0, stream>>>(ei, w, E, deg, cnt,
                                            W_orth, W11, W0, b0, scal, EB);
    k_scan1<<<NB, TPB, 0, stream>>>(cnt, off, bsum, N);
    k_scan2<<<1, 1024, 0, stream>>>(bsum, NB);
    k_scan3<<<NB, TPB, 0, stream>>>(off, pos, cnt, bsum, deg, dis, dinv, N, E);
    k_fill<<<EB, TPB, 0, stream>>>(ei, w, E, dis, pos, csr_src, csr_nrm);

    float2* prev = yA;
    float2* cur  = yB;
    for (int it = 0; it < 12; ++it) {
        k_gather<<<NB, TPB, 0, stream>>>(off, csr_src, csr_nrm, dinv, prev, cur, N);
        float2* tmp = prev; prev = cur; cur = tmp;
    }
    // after swaps: prev = y12, cur = y11
    k_final<<<NB, TPB, 0, stream>>>(prev, cur, scal, b11, (float*)d_out, N);
}

// Round 3
// 361.051 us; speedup vs baseline: 4.7503x; 1.3238x over previous
//
#include <hip/hip_runtime.h>
#include <hip/hip_bf16.h>

// Collapsed algebra:
//   out[i] = s * (A^12 x)[i] + t * (A^11 1)[i] + b11
// where A = D^{-1/2} (W + I) D^{-1/2} (self loops weight 1),
//   v = O_0 (O_1 (... (O_9 W11))),  O_k = Taylor_10(expm(Wk - Wk^T))
//   s = W0 . v,  t = b0 . v
//
// R1: 12x edge-scatter atomics -> one-time CSR build + 12x gathers.
// R2: halve build atomics (ticket trick, deg-from-CSR) + u-space norm:
//     u = dis .* y  ==>  u' = dis^2 .* (u + sum_e w_e u_{src_e})
//     so the gather uses RAW edge weights; un-scale once at the end.

#define TPB 256

// ---------------- v-chain: 100 sequential 64x64 matvecs, one block ----------
__device__ void v_chain(const float* __restrict__ W_orth,
                        const float* __restrict__ W11,
                        const float* __restrict__ W0,
                        const float* __restrict__ b0,
                        float* __restrict__ scal) {
    __shared__ float S[64 * 65];
    __shared__ float uvec[64];
    __shared__ float term[64];
    __shared__ float accv[64];
    const int tid = threadIdx.x;   // 256 threads

    if (tid < 64) uvec[tid] = W11[tid];
    __syncthreads();

    for (int k = 9; k >= 0; --k) {
        const float* Wk = W_orth + k * 4096;
        for (int e = tid; e < 4096; e += 256) {
            int i = e >> 6, j = e & 63;
            S[i * 65 + j] = Wk[i * 64 + j] - Wk[j * 64 + i];
        }
        __syncthreads();
        if (tid < 64) { term[tid] = uvec[tid]; accv[tid] = uvec[tid]; }
        __syncthreads();
        for (int t = 1; t <= 10; ++t) {
            const int r = tid >> 2, q = tid & 3;
            const int jb = q * 16;
            float p = 0.f;
            #pragma unroll
            for (int jj = 0; jj < 16; ++jj)
                p += S[r * 65 + jb + jj] * term[jb + jj];
            p += __shfl_xor(p, 1);
            p += __shfl_xor(p, 2);
            __syncthreads();
            if (q == 0) {
                float nt = p / (float)t;
                term[r] = nt;
                accv[r] += nt;
            }
            __syncthreads();
        }
        if (tid < 64) uvec[tid] = accv[tid];
        __syncthreads();
    }
    if (tid < 64) {
        float a = W0[tid] * uvec[tid];
        float b = b0[tid] * uvec[tid];
        #pragma unroll
        for (int off = 32; off; off >>= 1) {
            a += __shfl_down(a, off);
            b += __shfl_down(b, off);
        }
        if (tid == 0) { scal[0] = a; scal[1] = b; }
    }
}

// ---------------- kernels ---------------------------------------------------
__global__ void k_zero(int* __restrict__ cnt, int N) {
    int i = blockIdx.x * blockDim.x + threadIdx.x;
    if (i < N) cnt[i] = 0;
}

// per-edge: count in-edges, remember the returned slot (ticket).
// last block: Taylor v-chain.
__global__ void k_count(const int* __restrict__ ei, int E,
                        int* __restrict__ cnt, unsigned short* __restrict__ ticket,
                        const float* __restrict__ W_orth,
                        const float* __restrict__ W11,
                        const float* __restrict__ W0,
                        const float* __restrict__ b0,
                        float* __restrict__ scal, int edge_blocks) {
    if ((int)blockIdx.x == edge_blocks) {
        v_chain(W_orth, W11, W0, b0, scal);
        return;
    }
    int e = blockIdx.x * blockDim.x + threadIdx.x;
    if (e < E) {
        int c = ei[E + e];
        ticket[e] = (unsigned short)atomicAdd(&cnt[c], 1);
    }
}

// block-level inclusive scan of cnt -> off (partial), block sums -> bsum
__global__ void k_scan1(const int* __restrict__ cnt, int* __restrict__ off,
                        int* __restrict__ bsum, int N) {
    __shared__ int s[TPB];
    int t = threadIdx.x;
    int i = blockIdx.x * TPB + t;
    int v = (i < N) ? cnt[i] : 0;
    s[t] = v;
    __syncthreads();
    for (int o = 1; o < TPB; o <<= 1) {
        int u = (t >= o) ? s[t - o] : 0;
        __syncthreads();
        s[t] += u;
        __syncthreads();
    }
    if (i < N) off[i] = s[t];               // inclusive, block-local
    if (t == TPB - 1) bsum[blockIdx.x] = s[t];
}

// single-block exclusive scan of block sums (nb <= 1024)
__global__ void k_scan2(int* __restrict__ bsum, int nb) {
    __shared__ int s[1024];
    int t = threadIdx.x;
    int v = (t < nb) ? bsum[t] : 0;
    s[t] = v;
    __syncthreads();
    for (int o = 1; o < 1024; o <<= 1) {
        int u = (t >= o) ? s[t - o] : 0;
        __syncthreads();
        s[t] += u;
        __syncthreads();
    }
    if (t < nb) bsum[t] = s[t] - v;         // exclusive
}

// finalize: off -> global exclusive offsets
__global__ void k_scan3(int* __restrict__ off, const int* __restrict__ cnt,
                        const int* __restrict__ bsum, int N, int E) {
    int i = blockIdx.x * blockDim.x + threadIdx.x;
    if (i < N)
        off[i] = off[i] - cnt[i] + bsum[blockIdx.x];
    if (i == 0) off[N] = E;
}

// per-edge, ATOMIC-FREE: place (src, raw weight) into its CSR slot
__global__ void k_fill(const int* __restrict__ ei, const float* __restrict__ w,
                       int E, const int* __restrict__ off,
                       const unsigned short* __restrict__ ticket,
                       int2* __restrict__ csr) {
    int e = blockIdx.x * blockDim.x + threadIdx.x;
    if (e < E) {
        int r = ei[e], c = ei[E + e];
        int p = off[c] + (int)ticket[e];
        csr[p] = make_int2(r, __float_as_int(w[e]));
    }
}

// per-node: deg = 1 + row-sum of w; dis = rsqrt(deg); d2 = 1/deg;
// initialize u0 = dis .* [x, 1]
__global__ void k_rowdeg(const int* __restrict__ off, const int2* __restrict__ csr,
                         const float* __restrict__ x, float* __restrict__ dis,
                         float* __restrict__ d2, float2* __restrict__ u, int N) {
    int i = blockIdx.x * blockDim.x + threadIdx.x;
    if (i >= N) return;
    int s = off[i], eend = off[i + 1];
    float sum = 1.0f;                        // self-loop weight
    for (int k = s; k < eend; ++k)
        sum += __int_as_float(csr[k].y);
    float ds = rsqrtf(sum);
    dis[i] = ds;
    d2[i]  = 1.0f / sum;
    u[i] = make_float2(ds * x[i], ds);
}

// one propagation in u-space: u'_i = d2_i * (u_i + sum_row w_k * u_{src_k})
__global__ void k_gather(const int* __restrict__ off, const int2* __restrict__ csr,
                         const float* __restrict__ d2,
                         const float2* __restrict__ u, float2* __restrict__ out,
                         int N) {
    int i = blockIdx.x * blockDim.x + threadIdx.x;
    if (i >= N) return;
    int s = off[i], eend = off[i + 1];
    float2 ui = u[i];
    float ax = ui.x, ay = ui.y;
    for (int k = s; k < eend; ++k) {
        int2 c = csr[k];
        float n = __int_as_float(c.y);
        float2 v = u[c.x];
        ax = fmaf(n, v.x, ax);
        ay = fmaf(n, v.y, ay);
    }
    float sc = d2[i];
    out[i] = make_float2(sc * ax, sc * ay);
}

__global__ void k_final(const float2* __restrict__ u12, const float2* __restrict__ u11,
                        const float* __restrict__ dis,
                        const float* __restrict__ scal, const float* __restrict__ b11,
                        float* __restrict__ out, int N) {
    int i = blockIdx.x * blockDim.x + threadIdx.x;
    if (i < N)
        out[i] = (scal[0] * u12[i].x + scal[1] * u11[i].y) / dis[i] + b11[0];
}

// ---------------- launch ----------------------------------------------------
extern "C" void kernel_launch(void* const* d_in, const int* in_sizes, int n_in,
                              void* d_out, int out_size, void* d_ws, size_t ws_size,
                              hipStream_t stream) {
    const float* x      = (const float*)d_in[0];
    const int*   ei     = (const int*)d_in[1];
    const float* w      = (const float*)d_in[2];
    const float* W0     = (const float*)d_in[3];
    const float* b0     = (const float*)d_in[4];
    const float* W_orth = (const float*)d_in[5];
    const float* W11    = (const float*)d_in[6];
    const float* b11    = (const float*)d_in[7];

    const int N = in_sizes[0];          // 200000
    const int E = in_sizes[2];          // 1200000

    // workspace layout (8B-aligned chunks first)
    char* ws = (char*)d_ws;
    float2* uA     = (float2*)ws;        ws += (size_t)N * 8;
    float2* uB     = (float2*)ws;        ws += (size_t)N * 8;
    int2*   csr    = (int2*)ws;          ws += (size_t)E * 8;
    int*    cnt    = (int*)ws;           ws += (size_t)N * 4;
    int*    off    = (int*)ws;           ws += (size_t)(N + 2) * 4;
    float*  dis    = (float*)ws;         ws += (size_t)N * 4;
    float*  d2     = (float*)ws;         ws += (size_t)N * 4;
    int*    bsum   = (int*)ws;           ws += 1024 * 4;
    float*  scal   = (float*)ws;         ws += 16;
    unsigned short* ticket = (unsigned short*)ws;  ws += (size_t)E * 2;

    const int NB = (N + TPB - 1) / TPB;
    const int EB = (E + TPB - 1) / TPB;

    k_zero<<<NB, TPB, 0, stream>>>(cnt, N);
    k_count<<<EB + 1, TPB, 0, stream>>>(ei, E, cnt, ticket,
                                        W_orth, W11, W0, b0, scal, EB);
    k_scan1<<<NB, TPB, 0, stream>>>(cnt, off, bsum, N);
    k_scan2<<<1, 1024, 0, stream>>>(bsum, NB);
    k_scan3<<<NB, TPB, 0, stream>>>(off, cnt, bsum, N, E);
    k_fill<<<EB, TPB, 0, stream>>>(ei, w, E, off, ticket, csr);
    k_rowdeg<<<NB, TPB, 0, stream>>>(off, csr, x, dis, d2, uA, N);

    float2* prev = uA;
    float2* cur  = uB;
    for (int it = 0; it < 12; ++it) {
        k_gather<<<NB, TPB, 0, stream>>>(off, csr, d2, prev, cur, N);
        float2* tmp = prev; prev = cur; cur = tmp;
    }
    // after swaps: prev = u12, cur = u11
    k_final<<<NB, TPB, 0, stream>>>(prev, cur, dis, scal, b11, (float*)d_out, N);
}